// Round 9
// baseline (490.266 us; speedup 1.0000x reference)
//
#include <hip/hip_runtime.h>
#include <stdint.h>

#define NN 100000
#define NE 1600000
#define NBUK 782   // ceil(NN/128)
#define G 256      // pass-1/2 blocks
#define CHUNK 6250 // NE / G
#define GCHUNK 512 // gather LDS index-chunk per wave

typedef unsigned int u32;
typedef unsigned long long u64;
typedef unsigned short u16;
typedef short v8s __attribute__((ext_vector_type(8)));
typedef float v4f __attribute__((ext_vector_type(4)));

union U4S8 {
    uint4 u;
    v8s s;
};

__device__ __forceinline__ float bf2f(u16 u) {
    return __uint_as_float(((u32)u) << 16);
}
__device__ __forceinline__ u16 f2bf(float f) {
    u32 u = __float_as_uint(f);
    u = u + 0x7FFFu + ((u >> 16) & 1u);
    return (u16)(u >> 16);
}
__device__ __forceinline__ float lo16(u32 u) { return __uint_as_float(u << 16); }
__device__ __forceinline__ float hi16(u32 u) {
    return __uint_as_float(u & 0xFFFF0000u);
}

// Feature matrices (xb, h1, h2, mean) are stored GROUP-MAJOR:
//   [8 groups][NN+1 rows][8 u32]   (group = 16 channels = 8 u32 = 32B)
// so that the gather for group g (pinned to XCD g via blockIdx&7) has a
// 3.2MB working set that fits the XCD's private 4MB L2.
#define SL ((NN + 1) * 8)  // u32 stride of one group slice

// ---------------- dtype detection ----------------
__global__ void detect_kernel(const u32* __restrict__ ei,
                              const u32* __restrict__ x, int* flags) {
    __shared__ int bad64, badbf;
    int t = threadIdx.x;
    if (t == 0) { bad64 = 0; badbf = 0; }
    __syncthreads();
    if (ei[2 * t + 1] != 0u) atomicAdd(&bad64, 1);
    u32 d = x[t];
    u32 e = (d >> 7) & 0xFFu;
    if (e != 0u && (e < 96u || e > 160u)) atomicAdd(&badbf, 1);
    __syncthreads();
    if (t == 0) {
        flags[0] = (bad64 < 16) ? 1 : 0;
        flags[1] = (badbf < 16) ? 1 : 0;
    }
}

// ---------------- prep: x -> bf16 group-major (+ zero pad rows) ----------
__global__ void conv_x(const void* __restrict__ x, const int* __restrict__ flags,
                       u32* __restrict__ xbG, u32* __restrict__ h1G,
                       u32* __restrict__ h2G) {
    int i = blockIdx.x * 256 + threadIdx.x;  // over 8*(NN+1)*8
    if (i >= (NN + 1) * 64) return;
    int c = i & 7;
    int q = i >> 3;              // g*(NN+1) + node
    int node = q % (NN + 1);
    int g = q / (NN + 1);
    if (node == NN) {  // zero pad row of every group slice
        xbG[i] = 0;
        h1G[i] = 0;
        h2G[i] = 0;
        return;
    }
    int col = g * 8 + c;  // u32 column in the node-major view
    u32 o;
    if (flags[1]) {
        o = ((const u32*)x)[node * 64 + col];
    } else {
        float2 v = ((const float2*)x)[node * 64 + col];
        o = ((u32)f2bf(v.y) << 16) | (u32)f2bf(v.x);
    }
    xbG[i] = o;
}

// ---------------- prep: WT[c][k] = (k<128?Wr:Wl)[k%128][c], bias->f32 ----------
__global__ void wt_prep_all(const void* __restrict__ Wr0,
                            const void* __restrict__ Wl0,
                            const void* __restrict__ b0,
                            const void* __restrict__ Wr1,
                            const void* __restrict__ Wl1,
                            const void* __restrict__ b1,
                            const void* __restrict__ Wr2,
                            const void* __restrict__ Wl2,
                            const void* __restrict__ b2,
                            const int* __restrict__ flags,
                            u16* __restrict__ WT0, float* __restrict__ bf0,
                            u16* __restrict__ WT1, float* __restrict__ bf1,
                            u16* __restrict__ WT2, float* __restrict__ bf2_) {
    const void* Wr;
    const void* Wl;
    const void* bias;
    u16* WT;
    float* bias_f;
    int cout, t;
    if (blockIdx.x < 128) {
        Wr = Wr0; Wl = Wl0; bias = b0; WT = WT0; bias_f = bf0; cout = 128;
        t = blockIdx.x * 256 + threadIdx.x;
    } else if (blockIdx.x < 256) {
        Wr = Wr1; Wl = Wl1; bias = b1; WT = WT1; bias_f = bf1; cout = 128;
        t = (blockIdx.x - 128) * 256 + threadIdx.x;
    } else {
        Wr = Wr2; Wl = Wl2; bias = b2; WT = WT2; bias_f = bf2_; cout = 64;
        t = (blockIdx.x - 256) * 256 + threadIdx.x;
    }
    if (t < 256 * cout) {
        int k = t / cout, c = t % cout;
        const void* W = (k < 128) ? Wr : Wl;
        int kk = k & 127;
        float v;
        if (flags[1])
            v = bf2f(((const u16*)W)[kk * cout + c]);
        else
            v = ((const float*)W)[kk * cout + c];
        WT[c * 256 + k] = f2bf(v);
    }
    if (t < cout) {
        bias_f[t] =
            flags[1] ? bf2f(((const u16*)bias)[t]) : ((const float*)bias)[t];
    }
}

// ---------------- bucketed CSR build ----------------
// P1: per-block coarse histogram of dst>>7 into hist[b*G + g]
__global__ __launch_bounds__(256) void p1_hist(const void* __restrict__ ei,
                                               const int* __restrict__ flags,
                                               int* __restrict__ hist) {
    __shared__ int h[NBUK];
    int g = blockIdx.x, t = threadIdx.x;
    for (int b = t; b < NBUK; b += 256) h[b] = 0;
    __syncthreads();
    int e0 = g * CHUNK;
    int e1 = e0 + CHUNK;
    const int* p = (const int*)ei;
    if (flags[0]) {
        for (int e = e0 + t; e < e1; e += 256)
            atomicAdd(&h[p[2 * (NE + e)] >> 7], 1);
    } else {
        for (int e = e0 + t; e < e1; e += 256)
            atomicAdd(&h[p[NE + e] >> 7], 1);
    }
    __syncthreads();
    for (int b = t; b < NBUK; b += 256) hist[b * G + g] = h[b];
}

// generic scan: 1024 elements per block (4/thread)
__global__ void scan_block_g(const int* __restrict__ in, int* __restrict__ out,
                             int* __restrict__ bsums, int n) {
    __shared__ int sS[256];
    int t = threadIdx.x;
    int base = blockIdx.x * 1024 + t * 4;
    int c[4];
#pragma unroll
    for (int i = 0; i < 4; ++i) c[i] = (base + i < n) ? in[base + i] : 0;
    int s = c[0] + c[1] + c[2] + c[3];
    sS[t] = s;
    __syncthreads();
    for (int dlt = 1; dlt < 256; dlt <<= 1) {
        int v = (t >= dlt) ? sS[t - dlt] : 0;
        __syncthreads();
        sS[t] += v;
        __syncthreads();
    }
    int run = sS[t] - s;
    if (t == 255) bsums[blockIdx.x] = sS[255];
#pragma unroll
    for (int i = 0; i < 4; ++i) {
        if (base + i < n) out[base + i] = run;
        run += c[i];
    }
}

__global__ void scan_top_g(int* bsums, int nb) {
    __shared__ int sS[256];
    int t = threadIdx.x;
    int v = (t < nb) ? bsums[t] : 0;
    sS[t] = v;
    __syncthreads();
    for (int d = 1; d < 256; d <<= 1) {
        int u = (t >= d) ? sS[t - d] : 0;
        __syncthreads();
        sS[t] += u;
        __syncthreads();
    }
    if (t < nb) bsums[t] = sS[t] - v;
}

__global__ void scan_add_g(int* __restrict__ out, const int* __restrict__ bsums,
                           int n) {
    int i = blockIdx.x * 256 + threadIdx.x;
    if (i < n) out[i] += bsums[i >> 10];
}

// P2: scatter packed (src | (dst&127)<<17) into bucket-sorted ebuf via LDS
// cursors. src < 2^17 (NN=100000), so one u32 halves p2/p3 traffic vs int2.
__global__ __launch_bounds__(256) void p2_scatter(const void* __restrict__ ei,
                                                  const int* __restrict__ flags,
                                                  const int* __restrict__ histS,
                                                  u32* __restrict__ ebuf) {
    __shared__ int cur[NBUK];
    int g = blockIdx.x, t = threadIdx.x;
    for (int b = t; b < NBUK; b += 256) cur[b] = histS[b * G + g];
    __syncthreads();
    int e0 = g * CHUNK;
    int e1 = e0 + CHUNK;
    const int* p = (const int*)ei;
    int is64 = flags[0];
    for (int e = e0 + t; e < e1; e += 256) {
        int s, d;
        if (is64) {
            s = p[2 * e];
            d = p[2 * (NE + e)];
        } else {
            s = p[e];
            d = p[NE + e];
        }
        int pos = atomicAdd(&cur[d >> 7], 1);
        ebuf[pos] = (u32)s | ((u32)(d & 127) << 17);
    }
}

// P3: one block per bucket (128 nodes): exact counts, local scan -> off[],
// then scatter src into the bucket's contiguous CSR region.
__global__ __launch_bounds__(256) void p3_build(const int* __restrict__ histS,
                                                const u32* __restrict__ ebuf,
                                                int* __restrict__ off,
                                                int* __restrict__ ssrc) {
    __shared__ int cnt[128], pref[128], cur[128];
    int b = blockIdx.x, t = threadIdx.x;
    int node0 = b << 7;
    int bs = histS[b * G];
    int be = (b == NBUK - 1) ? NE : histS[(b + 1) * G];
    if (t < 128) cnt[t] = 0;
    __syncthreads();
    for (int e = bs + t; e < be; e += 256)
        atomicAdd(&cnt[ebuf[e] >> 17], 1);
    __syncthreads();
    if (t < 128) pref[t] = cnt[t];
    __syncthreads();
    for (int d = 1; d < 128; d <<= 1) {
        int v = 0;
        if (t < 128 && t >= d) v = pref[t - d];
        __syncthreads();
        if (t < 128) pref[t] += v;
        __syncthreads();
    }
    if (t < 128) {
        int ex = pref[t] - cnt[t];
        cur[t] = ex;
        int node = node0 + t;
        if (node < NN) off[node] = bs + ex;
    }
    if (b == NBUK - 1 && t == 0) off[NN] = NE;
    __syncthreads();
    for (int e = bs + t; e < be; e += 256) {
        u32 v = ebuf[e];
        int pos = atomicAdd(&cur[v >> 17], 1);
        ssrc[bs + pos] = (int)(v & 0x1FFFFu);
    }
}

// ---------------- mean aggregation, channel-split across XCDs -------------
// v7: same structure as v6 (16 node-slots x 4 chan-lanes, LDS-staged
// pre-scaled indices, unroll 16 loads-first) PLUS non-temporal hints on the
// two streaming access patterns: ssrc staging loads (6.4MB/XCD streamed) and
// meanB output stores (3.2MB/XCD). Theory (r8): these streams thrash the
// 4MB XCD L2 that must hold the 3.2MB feature slice — every evicted feature
// line is a ~600cy L3 refetch on the in-order-vmcnt critical path. nt keeps
// the L2 reserved for features. g = blockIdx&7 pins group g to XCD g.
__global__ __launch_bounds__(256) void gather_mean_g(
    const u32* __restrict__ featG, const int* __restrict__ off,
    const int* __restrict__ ssrc, u32* __restrict__ meanG) {
    __shared__ u32 sidx[4][GCHUNK];
    const int g = blockIdx.x & 7;
    const int nb = blockIdx.x >> 3;      // 0..1562
    const int wv = threadIdx.x >> 6;
    const int lane = threadIdx.x & 63;
    const int ns = lane >> 2;            // node slot 0..15
    const int c = lane & 3;              // uint2 column 0..3
    const int node0 = nb * 64 + wv * 16;
    if (node0 >= NN) return;             // tail waves empty
    const char* fgb = (const char*)(featG + (size_t)g * SL);
    u32* mg = meanG + (size_t)g * SL;
    const u32 coff = (u32)(c * 8);

    const int e0 = __builtin_amdgcn_readfirstlane(off[node0]);
    const int e1 = __builtin_amdgcn_readfirstlane(off[node0 + 16]);
    const int node = node0 + ns;
    const int myo0 = off[node];
    const int myo1 = off[node + 1];
    const int cnt = myo1 - myo0;

#define LD2(v) (*(const uint2*)(fgb + (size_t)((v) + coff)))
#define ACC2(u)                    \
    do {                           \
        a0 += lo16((u).x);         \
        a1 += hi16((u).x);         \
        a2 += lo16((u).y);         \
        a3 += hi16((u).y);         \
    } while (0)

    float a0 = 0.f, a1 = 0.f, a2 = 0.f, a3 = 0.f;
    for (int cb = e0; cb < e1; cb += GCHUNK) {
        const int m = min(GCHUNK, e1 - cb);
        // cooperative coalesced stage of this chunk's indices (pre-scaled
        // to byte offsets) into LDS — NON-TEMPORAL (pure stream, keep out
        // of the XCD L2)
#pragma unroll
        for (int r = 0; r < GCHUNK / 64; ++r) {
            int i = r * 64 + lane;
            u32 v = (u32)__builtin_nontemporal_load(
                        ssrc + (cb + ((i < m) ? i : 0)))
                    << 5;
            sidx[wv][i] = v;
        }
        __builtin_amdgcn_s_waitcnt(0);  // vm+lgkm drained: stage visible
        __builtin_amdgcn_wave_barrier();
        int s0 = myo0 - cb; s0 = (s0 > 0) ? s0 : 0;
        int s1 = myo1 - cb; s1 = (s1 < m) ? s1 : m;
        int j = s0;
        for (; j + 16 <= s1; j += 16) {
            u32 v0 = sidx[wv][j];
            u32 v1 = sidx[wv][j + 1];
            u32 v2 = sidx[wv][j + 2];
            u32 v3 = sidx[wv][j + 3];
            u32 v4 = sidx[wv][j + 4];
            u32 v5 = sidx[wv][j + 5];
            u32 v6 = sidx[wv][j + 6];
            u32 v7 = sidx[wv][j + 7];
            u32 v8 = sidx[wv][j + 8];
            u32 v9 = sidx[wv][j + 9];
            u32 va = sidx[wv][j + 10];
            u32 vb = sidx[wv][j + 11];
            u32 vc = sidx[wv][j + 12];
            u32 vd = sidx[wv][j + 13];
            u32 ve = sidx[wv][j + 14];
            u32 vf = sidx[wv][j + 15];
            uint2 u0 = LD2(v0);
            uint2 u1 = LD2(v1);
            uint2 u2 = LD2(v2);
            uint2 u3 = LD2(v3);
            uint2 u4 = LD2(v4);
            uint2 u5 = LD2(v5);
            uint2 u6 = LD2(v6);
            uint2 u7 = LD2(v7);
            uint2 u8 = LD2(v8);
            uint2 u9 = LD2(v9);
            uint2 ua = LD2(va);
            uint2 ub = LD2(vb);
            uint2 uc = LD2(vc);
            uint2 ud = LD2(vd);
            uint2 ue = LD2(ve);
            uint2 uf = LD2(vf);
            ACC2(u0); ACC2(u1); ACC2(u2); ACC2(u3);
            ACC2(u4); ACC2(u5); ACC2(u6); ACC2(u7);
            ACC2(u8); ACC2(u9); ACC2(ua); ACC2(ub);
            ACC2(uc); ACC2(ud); ACC2(ue); ACC2(uf);
        }
        for (; j + 8 <= s1; j += 8) {
            u32 v0 = sidx[wv][j];
            u32 v1 = sidx[wv][j + 1];
            u32 v2 = sidx[wv][j + 2];
            u32 v3 = sidx[wv][j + 3];
            u32 v4 = sidx[wv][j + 4];
            u32 v5 = sidx[wv][j + 5];
            u32 v6 = sidx[wv][j + 6];
            u32 v7 = sidx[wv][j + 7];
            uint2 u0 = LD2(v0);
            uint2 u1 = LD2(v1);
            uint2 u2 = LD2(v2);
            uint2 u3 = LD2(v3);
            uint2 u4 = LD2(v4);
            uint2 u5 = LD2(v5);
            uint2 u6 = LD2(v6);
            uint2 u7 = LD2(v7);
            ACC2(u0); ACC2(u1); ACC2(u2); ACC2(u3);
            ACC2(u4); ACC2(u5); ACC2(u6); ACC2(u7);
        }
        for (; j + 4 <= s1; j += 4) {
            u32 v0 = sidx[wv][j];
            u32 v1 = sidx[wv][j + 1];
            u32 v2 = sidx[wv][j + 2];
            u32 v3 = sidx[wv][j + 3];
            uint2 u0 = LD2(v0);
            uint2 u1 = LD2(v1);
            uint2 u2 = LD2(v2);
            uint2 u3 = LD2(v3);
            ACC2(u0); ACC2(u1); ACC2(u2); ACC2(u3);
        }
        for (; j < s1; ++j) {
            u32 v0 = sidx[wv][j];
            uint2 u0 = LD2(v0);
            ACC2(u0);
        }
        __builtin_amdgcn_wave_barrier();  // reads done before next-chunk writes
    }
#undef LD2
#undef ACC2
    float inv = 1.0f / (float)(cnt > 0 ? cnt : 1);
    u32 ox = ((u32)f2bf(a1 * inv) << 16) | (u32)f2bf(a0 * inv);
    u32 oy = ((u32)f2bf(a3 * inv) << 16) | (u32)f2bf(a2 * inv);
    // NON-TEMPORAL output store (3.2MB/XCD stream; consumed by sage_mfma
    // via L3, keep out of this XCD's L2)
    u64 ov = ((u64)oy << 32) | (u64)ox;
    __builtin_nontemporal_store(ov, (u64*)(mg + (size_t)node * 8 + c * 2));
}

// ---------------- MFMA GEMM: out = [self|mean](bf16) @ WT^T + b ----------------
// swapped-operand MFMA (D[ch][node]); WT staged once per block in swizzled
// LDS; 64 rows per wave. self/mean are group-major; A-fragment 16B chunks
// lie inside one group slice: gg = (ks&3)*2 + (quad>>1), col = (quad&1)*4.
template <int COUT, bool RELU, bool FINAL>
__global__ __launch_bounds__(256, 2) void sage_mfma(
    const u32* __restrict__ selfG, const u32* __restrict__ meanG,
    const u16* __restrict__ WT, const float* __restrict__ bias_f,
    void* __restrict__ out, const int* __restrict__ flags) {
    constexpr int CT = COUT / 16;            // 8 (L0/L1) or 4 (L2)
    __shared__ u16 wlds[256 * COUT];         // 64KB / 32KB, swizzled
    const int tid = threadIdx.x;
    const int wave = tid >> 6;
    const int lane = tid & 63;
    const int n16 = lane & 15;
    const int quad = lane >> 4;
    const int bfin = flags[1];

    // ---- stage WT into LDS, XOR-swizzled
    {
        const uint4* src = (const uint4*)WT;
        char* wb = (char*)wlds;
        constexpr int NITER = (COUT * 32) / 256;  // 16 or 8
#pragma unroll
        for (int i = 0; i < NITER; ++i) {
            int idx = i * 256 + tid;
            int c = idx >> 5;
            int off = (idx & 31) << 4;
            *(uint4*)(wb + c * 512 + (off ^ ((c & 7) << 4))) = src[idx];
        }
    }
    __syncthreads();

    // ---- per-lane A bases (4 M-tiles of 16 rows; n16 picks the row)
    const int rowb = blockIdx.x * 256 + wave * 64 + n16;
    const int gq = quad >> 1;
    const int wcol = (quad & 1) * 4;
    int rbase[4];
#pragma unroll
    for (int mt = 0; mt < 4; ++mt) {
        int r = rowb + mt * 16;
        r = (r < NN) ? r : (NN - 1);
        rbase[mt] = r * 8 + gq * SL + wcol;  // u32 index within (ks&3) pair
    }

    v4f acc[4][CT];
#pragma unroll
    for (int mt = 0; mt < 4; ++mt)
#pragma unroll
        for (int ct = 0; ct < CT; ++ct) acc[mt][ct] = (v4f)(0.f);

    const char* wb = (const char*)wlds;
    const int swz = (n16 & 7) << 4;
#pragma unroll
    for (int ks = 0; ks < 8; ++ks) {
        const u32* bp = (ks < 4) ? selfG : meanG;
        const int kof = (ks & 3) * 2 * SL;
        U4S8 nf[4];
#pragma unroll
        for (int mt = 0; mt < 4; ++mt)
            nf[mt].u = *(const uint4*)(bp + kof + rbase[mt]);
        U4S8 wf[CT];
#pragma unroll
        for (int ct = 0; ct < CT; ++ct) {
            int addr = (ct * 16 + n16) * 512 + ((ks * 64 + quad * 16) ^ swz);
            wf[ct].u = *(const uint4*)(wb + addr);
        }
#pragma unroll
        for (int mt = 0; mt < 4; ++mt)
#pragma unroll
            for (int ct = 0; ct < CT; ++ct)
                acc[mt][ct] = __builtin_amdgcn_mfma_f32_16x16x32_bf16(
                    wf[ct].s, nf[mt].s, acc[mt][ct], 0, 0, 0);
    }

    // ---- epilogue: lane holds node=rowb+mt*16, channels ct*16+quad*4+[0..3]
    float4 bv[CT];
#pragma unroll
    for (int ct = 0; ct < CT; ++ct)
        bv[ct] = *(const float4*)&bias_f[ct * 16 + quad * 4];

#pragma unroll
    for (int mt = 0; mt < 4; ++mt) {
        int row = rowb + mt * 16;
        if (row < NN) {
#pragma unroll
            for (int ct = 0; ct < CT; ++ct) {
                float v0 = acc[mt][ct][0] + bv[ct].x;
                float v1 = acc[mt][ct][1] + bv[ct].y;
                float v2 = acc[mt][ct][2] + bv[ct].z;
                float v3 = acc[mt][ct][3] + bv[ct].w;
                if (RELU) {
                    v0 = fmaxf(v0, 0.f);
                    v1 = fmaxf(v1, 0.f);
                    v2 = fmaxf(v2, 0.f);
                    v3 = fmaxf(v3, 0.f);
                }
                if (FINAL && !bfin) {
                    float4 o = {v0, v1, v2, v3};
                    *(float4*)((float*)out + (size_t)row * COUT + ct * 16 +
                               quad * 4) = o;
                } else {
                    uint2 o;
                    o.x = (u32)f2bf(v0) | ((u32)f2bf(v1) << 16);
                    o.y = (u32)f2bf(v2) | ((u32)f2bf(v3) << 16);
                    if (FINAL) {
                        // external bf16 output stays node-major
                        *(uint2*)((u16*)out + (size_t)row * COUT + ct * 16 +
                                  quad * 4) = o;
                    } else {
                        // group-major h write: group = ct, cols quad*2..+1
                        *(uint2*)((u32*)out + (size_t)ct * SL + (size_t)row * 8 +
                                  quad * 2) = o;
                    }
                }
            }
        }
    }
}

extern "C" void kernel_launch(void* const* d_in, const int* in_sizes, int n_in,
                              void* d_out, int out_size, void* d_ws,
                              size_t ws_size, hipStream_t stream) {
    const void* x = d_in[0];
    const void* ei = d_in[1];
    const void* Wl0 = d_in[2];
    const void* Wr0 = d_in[3];
    const void* b0 = d_in[4];
    const void* Wl1 = d_in[5];
    const void* Wr1 = d_in[6];
    const void* b1 = d_in[7];
    const void* Wl2 = d_in[8];
    const void* Wr2 = d_in[9];
    const void* b2 = d_in[10];

    char* ws = (char*)d_ws;
    size_t o = 0;
    auto alloc = [&](size_t bytes) {
        void* p = ws + o;
        o = (o + bytes + 511) & ~(size_t)511;
        return p;
    };
    int* flags = (int*)alloc(16);
    int* hist = (int*)alloc((size_t)NBUK * G * 4);
    int* bsums = (int*)alloc(256 * 4);
    int* off = (int*)alloc((NN + 1) * 4);
    int* ssrc = (int*)alloc((size_t)NE * 4);
    u32* ebuf = (u32*)alloc((size_t)NE * 4);             // packed src|dloc
    u32* xb = (u32*)alloc((size_t)(NN + 1) * 64 * 4);    // group-major + pad
    u32* meanB = (u32*)alloc((size_t)(NN + 1) * 64 * 4); // group-major + pad
    u32* h1 = (u32*)alloc((size_t)(NN + 1) * 64 * 4);
    u32* h2 = (u32*)alloc((size_t)(NN + 1) * 64 * 4);
    u16* WT0 = (u16*)alloc(256 * 128 * 2);
    u16* WT1 = (u16*)alloc(256 * 128 * 2);
    u16* WT2 = (u16*)alloc(256 * 64 * 2);
    float* bf0 = (float*)alloc(128 * 4);
    float* bf1 = (float*)alloc(128 * 4);
    float* bf2_ = (float*)alloc(64 * 4);

    constexpr int L = NBUK * G;              // 200192
    constexpr int NBLK = (L + 1023) / 1024;  // 196 (<= 256)
    constexpr int RB = (NN + 255) / 256;     // 391 (256 rows / block)
    constexpr int GB = 8 * ((NN + 63) / 64); // 12504 gather blocks

    detect_kernel<<<1, 256, 0, stream>>>((const u32*)ei, (const u32*)x, flags);
    conv_x<<<((NN + 1) * 64 + 255) / 256, 256, 0, stream>>>(x, flags, xb, h1,
                                                            h2);
    wt_prep_all<<<320, 256, 0, stream>>>(Wr0, Wl0, b0, Wr1, Wl1, b1, Wr2, Wl2,
                                         b2, flags, WT0, bf0, WT1, bf1, WT2,
                                         bf2_);

    // bucketed CSR build (packed u32 ebuf)
    p1_hist<<<G, 256, 0, stream>>>(ei, flags, hist);
    scan_block_g<<<NBLK, 256, 0, stream>>>(hist, hist, bsums, L);
    scan_top_g<<<1, 256, 0, stream>>>(bsums, NBLK);
    scan_add_g<<<(L + 255) / 256, 256, 0, stream>>>(hist, bsums, L);
    p2_scatter<<<G, 256, 0, stream>>>(ei, flags, hist, ebuf);
    p3_build<<<NBUK, 256, 0, stream>>>(hist, ebuf, off, ssrc);

    // layer 0
    gather_mean_g<<<GB, 256, 0, stream>>>(xb, off, ssrc, meanB);
    sage_mfma<128, true, false><<<RB, 256, 0, stream>>>(xb, meanB, WT0, bf0,
                                                        h1, flags);
    // layer 1
    gather_mean_g<<<GB, 256, 0, stream>>>(h1, off, ssrc, meanB);
    sage_mfma<128, true, false><<<RB, 256, 0, stream>>>(h1, meanB, WT1, bf1,
                                                        h2, flags);
    // layer 2
    gather_mean_g<<<GB, 256, 0, stream>>>(h2, off, ssrc, meanB);
    sage_mfma<64, false, true><<<RB, 256, 0, stream>>>(h2, meanB, WT2, bf2_,
                                                       d_out, flags);
}

// Round 10
// 415.286 us; speedup vs baseline: 1.1805x; 1.1805x over previous
//
#include <hip/hip_runtime.h>
#include <stdint.h>

#define NN 100000
#define NE 1600000
#define NBUK 782   // ceil(NN/128)
#define G 512      // pass-1/2 blocks (2 blocks/CU — p1/p2 are latency-bound)
#define CHUNK 3125 // NE / G
#define GCHUNK 512 // gather LDS index-chunk per wave

typedef unsigned int u32;
typedef unsigned short u16;
typedef short v8s __attribute__((ext_vector_type(8)));
typedef float v4f __attribute__((ext_vector_type(4)));

union U4S8 {
    uint4 u;
    v8s s;
};

__device__ __forceinline__ float bf2f(u16 u) {
    return __uint_as_float(((u32)u) << 16);
}
__device__ __forceinline__ u16 f2bf(float f) {
    u32 u = __float_as_uint(f);
    u = u + 0x7FFFu + ((u >> 16) & 1u);
    return (u16)(u >> 16);
}
__device__ __forceinline__ float lo16(u32 u) { return __uint_as_float(u << 16); }
__device__ __forceinline__ float hi16(u32 u) {
    return __uint_as_float(u & 0xFFFF0000u);
}

// Feature matrices (xb, h1, h2, mean) are stored GROUP-MAJOR:
//   [8 groups][NN+1 rows][8 u32]   (group = 16 channels = 8 u32 = 32B)
// so that the gather for group g (pinned to XCD g via blockIdx&7) has a
// 3.2MB working set that fits the XCD's private 4MB L2.
#define SL ((NN + 1) * 8)  // u32 stride of one group slice

// ---------------- dtype detection ----------------
__global__ void detect_kernel(const u32* __restrict__ ei,
                              const u32* __restrict__ x, int* flags) {
    __shared__ int bad64, badbf;
    int t = threadIdx.x;
    if (t == 0) { bad64 = 0; badbf = 0; }
    __syncthreads();
    if (ei[2 * t + 1] != 0u) atomicAdd(&bad64, 1);
    u32 d = x[t];
    u32 e = (d >> 7) & 0xFFu;
    if (e != 0u && (e < 96u || e > 160u)) atomicAdd(&badbf, 1);
    __syncthreads();
    if (t == 0) {
        flags[0] = (bad64 < 16) ? 1 : 0;
        flags[1] = (badbf < 16) ? 1 : 0;
    }
}

// ---------------- prep: x -> bf16 group-major (+ zero pad rows) ----------
__global__ void conv_x(const void* __restrict__ x, const int* __restrict__ flags,
                       u32* __restrict__ xbG, u32* __restrict__ h1G,
                       u32* __restrict__ h2G) {
    int i = blockIdx.x * 256 + threadIdx.x;  // over 8*(NN+1)*8
    if (i >= (NN + 1) * 64) return;
    int c = i & 7;
    int q = i >> 3;              // g*(NN+1) + node
    int node = q % (NN + 1);
    int g = q / (NN + 1);
    if (node == NN) {  // zero pad row of every group slice
        xbG[i] = 0;
        h1G[i] = 0;
        h2G[i] = 0;
        return;
    }
    int col = g * 8 + c;  // u32 column in the node-major view
    u32 o;
    if (flags[1]) {
        o = ((const u32*)x)[node * 64 + col];
    } else {
        float2 v = ((const float2*)x)[node * 64 + col];
        o = ((u32)f2bf(v.y) << 16) | (u32)f2bf(v.x);
    }
    xbG[i] = o;
}

// ---------------- prep: WT[c][k] = (k<128?Wr:Wl)[k%128][c], bias->f32 ----------
__global__ void wt_prep_all(const void* __restrict__ Wr0,
                            const void* __restrict__ Wl0,
                            const void* __restrict__ b0,
                            const void* __restrict__ Wr1,
                            const void* __restrict__ Wl1,
                            const void* __restrict__ b1,
                            const void* __restrict__ Wr2,
                            const void* __restrict__ Wl2,
                            const void* __restrict__ b2,
                            const int* __restrict__ flags,
                            u16* __restrict__ WT0, float* __restrict__ bf0,
                            u16* __restrict__ WT1, float* __restrict__ bf1,
                            u16* __restrict__ WT2, float* __restrict__ bf2_) {
    const void* Wr;
    const void* Wl;
    const void* bias;
    u16* WT;
    float* bias_f;
    int cout, t;
    if (blockIdx.x < 128) {
        Wr = Wr0; Wl = Wl0; bias = b0; WT = WT0; bias_f = bf0; cout = 128;
        t = blockIdx.x * 256 + threadIdx.x;
    } else if (blockIdx.x < 256) {
        Wr = Wr1; Wl = Wl1; bias = b1; WT = WT1; bias_f = bf1; cout = 128;
        t = (blockIdx.x - 128) * 256 + threadIdx.x;
    } else {
        Wr = Wr2; Wl = Wl2; bias = b2; WT = WT2; bias_f = bf2_; cout = 64;
        t = (blockIdx.x - 256) * 256 + threadIdx.x;
    }
    if (t < 256 * cout) {
        int k = t / cout, c = t % cout;
        const void* W = (k < 128) ? Wr : Wl;
        int kk = k & 127;
        float v;
        if (flags[1])
            v = bf2f(((const u16*)W)[kk * cout + c]);
        else
            v = ((const float*)W)[kk * cout + c];
        WT[c * 256 + k] = f2bf(v);
    }
    if (t < cout) {
        bias_f[t] =
            flags[1] ? bf2f(((const u16*)bias)[t]) : ((const float*)bias)[t];
    }
}

// ---------------- bucketed CSR build ----------------
// P1: per-block coarse histogram of dst>>7 into hist[b*G + g]
__global__ __launch_bounds__(256) void p1_hist(const void* __restrict__ ei,
                                               const int* __restrict__ flags,
                                               int* __restrict__ hist) {
    __shared__ int h[NBUK];
    int g = blockIdx.x, t = threadIdx.x;
    for (int b = t; b < NBUK; b += 256) h[b] = 0;
    __syncthreads();
    int e0 = g * CHUNK;
    int e1 = e0 + CHUNK;
    const int* p = (const int*)ei;
    if (flags[0]) {
        for (int e = e0 + t; e < e1; e += 256)
            atomicAdd(&h[p[2 * (NE + e)] >> 7], 1);
    } else {
        for (int e = e0 + t; e < e1; e += 256)
            atomicAdd(&h[p[NE + e] >> 7], 1);
    }
    __syncthreads();
    for (int b = t; b < NBUK; b += 256) hist[b * G + g] = h[b];
}

// generic scan: 2048 elements per block (8/thread)
__global__ void scan_block_g(const int* __restrict__ in, int* __restrict__ out,
                             int* __restrict__ bsums, int n) {
    __shared__ int sS[256];
    int t = threadIdx.x;
    int base = blockIdx.x * 2048 + t * 8;
    int c[8];
#pragma unroll
    for (int i = 0; i < 8; ++i) c[i] = (base + i < n) ? in[base + i] : 0;
    int s = c[0] + c[1] + c[2] + c[3] + c[4] + c[5] + c[6] + c[7];
    sS[t] = s;
    __syncthreads();
    for (int dlt = 1; dlt < 256; dlt <<= 1) {
        int v = (t >= dlt) ? sS[t - dlt] : 0;
        __syncthreads();
        sS[t] += v;
        __syncthreads();
    }
    int run = sS[t] - s;
    if (t == 255) bsums[blockIdx.x] = sS[255];
#pragma unroll
    for (int i = 0; i < 8; ++i) {
        if (base + i < n) out[base + i] = run;
        run += c[i];
    }
}

__global__ void scan_top_g(int* bsums, int nb) {
    __shared__ int sS[256];
    int t = threadIdx.x;
    int v = (t < nb) ? bsums[t] : 0;
    sS[t] = v;
    __syncthreads();
    for (int d = 1; d < 256; d <<= 1) {
        int u = (t >= d) ? sS[t - d] : 0;
        __syncthreads();
        sS[t] += u;
        __syncthreads();
    }
    if (t < nb) bsums[t] = sS[t] - v;
}

__global__ void scan_add_g(int* __restrict__ out, const int* __restrict__ bsums,
                           int n) {
    int i = blockIdx.x * 256 + threadIdx.x;
    if (i < n) out[i] += bsums[i >> 11];
}

// P2: scatter packed (src | (dst&127)<<17) into bucket-sorted ebuf via LDS
// cursors. src < 2^17 (NN=100000), so one u32 halves p2/p3 traffic vs int2.
__global__ __launch_bounds__(256) void p2_scatter(const void* __restrict__ ei,
                                                  const int* __restrict__ flags,
                                                  const int* __restrict__ histS,
                                                  u32* __restrict__ ebuf) {
    __shared__ int cur[NBUK];
    int g = blockIdx.x, t = threadIdx.x;
    for (int b = t; b < NBUK; b += 256) cur[b] = histS[b * G + g];
    __syncthreads();
    int e0 = g * CHUNK;
    int e1 = e0 + CHUNK;
    const int* p = (const int*)ei;
    int is64 = flags[0];
    for (int e = e0 + t; e < e1; e += 256) {
        int s, d;
        if (is64) {
            s = p[2 * e];
            d = p[2 * (NE + e)];
        } else {
            s = p[e];
            d = p[NE + e];
        }
        int pos = atomicAdd(&cur[d >> 7], 1);
        ebuf[pos] = (u32)s | ((u32)(d & 127) << 17);
    }
}

// P3: one block per bucket (128 nodes): exact counts, local scan -> off[],
// then scatter src into the bucket's contiguous CSR region.
__global__ __launch_bounds__(256) void p3_build(const int* __restrict__ histS,
                                                const u32* __restrict__ ebuf,
                                                int* __restrict__ off,
                                                int* __restrict__ ssrc) {
    __shared__ int cnt[128], pref[128], cur[128];
    int b = blockIdx.x, t = threadIdx.x;
    int node0 = b << 7;
    int bs = histS[b * G];
    int be = (b == NBUK - 1) ? NE : histS[(b + 1) * G];
    if (t < 128) cnt[t] = 0;
    __syncthreads();
    for (int e = bs + t; e < be; e += 256)
        atomicAdd(&cnt[ebuf[e] >> 17], 1);
    __syncthreads();
    if (t < 128) pref[t] = cnt[t];
    __syncthreads();
    for (int d = 1; d < 128; d <<= 1) {
        int v = 0;
        if (t < 128 && t >= d) v = pref[t - d];
        __syncthreads();
        if (t < 128) pref[t] += v;
        __syncthreads();
    }
    if (t < 128) {
        int ex = pref[t] - cnt[t];
        cur[t] = ex;
        int node = node0 + t;
        if (node < NN) off[node] = bs + ex;
    }
    if (b == NBUK - 1 && t == 0) off[NN] = NE;
    __syncthreads();
    for (int e = bs + t; e < be; e += 256) {
        u32 v = ebuf[e];
        int pos = atomicAdd(&cur[v >> 17], 1);
        ssrc[bs + pos] = (int)(v & 0x1FFFFu);
    }
}

// ---------------- mean aggregation, channel-split across XCDs -------------
// v6 (round-8 known-good, 68.3us): wave = 16 node-slots x 4 chan-lanes
// (uint2 per edge). Indices staged in LDS pre-scaled to byte offsets.
// Unroll 16 loads-first. g = blockIdx&7 pins group g's 3.2MB slice to
// XCD g's L2. NOTE (r9): non-temporal hints on ssrc/meanB REGRESSED
// (68.3 -> 88.4us) — keep plain loads/stores.
__global__ __launch_bounds__(256) void gather_mean_g(
    const u32* __restrict__ featG, const int* __restrict__ off,
    const int* __restrict__ ssrc, u32* __restrict__ meanG) {
    __shared__ u32 sidx[4][GCHUNK];
    const int g = blockIdx.x & 7;
    const int nb = blockIdx.x >> 3;      // 0..1562
    const int wv = threadIdx.x >> 6;
    const int lane = threadIdx.x & 63;
    const int ns = lane >> 2;            // node slot 0..15
    const int c = lane & 3;              // uint2 column 0..3
    const int node0 = nb * 64 + wv * 16;
    if (node0 >= NN) return;             // tail waves empty
    const char* fgb = (const char*)(featG + (size_t)g * SL);
    u32* mg = meanG + (size_t)g * SL;
    const u32 coff = (u32)(c * 8);

    const int e0 = __builtin_amdgcn_readfirstlane(off[node0]);
    const int e1 = __builtin_amdgcn_readfirstlane(off[node0 + 16]);
    const int node = node0 + ns;
    const int myo0 = off[node];
    const int myo1 = off[node + 1];
    const int cnt = myo1 - myo0;

#define LD2(v) (*(const uint2*)(fgb + (size_t)((v) + coff)))
#define ACC2(u)                    \
    do {                           \
        a0 += lo16((u).x);         \
        a1 += hi16((u).x);         \
        a2 += lo16((u).y);         \
        a3 += hi16((u).y);         \
    } while (0)

    float a0 = 0.f, a1 = 0.f, a2 = 0.f, a3 = 0.f;
    for (int cb = e0; cb < e1; cb += GCHUNK) {
        const int m = min(GCHUNK, e1 - cb);
        // cooperative coalesced stage of this chunk's indices (pre-scaled
        // to byte offsets) into LDS
#pragma unroll
        for (int r = 0; r < GCHUNK / 64; ++r) {
            int i = r * 64 + lane;
            u32 v = (u32)ssrc[cb + ((i < m) ? i : 0)] << 5;
            sidx[wv][i] = v;
        }
        __builtin_amdgcn_s_waitcnt(0);  // vm+lgkm drained: stage visible
        __builtin_amdgcn_wave_barrier();
        int s0 = myo0 - cb; s0 = (s0 > 0) ? s0 : 0;
        int s1 = myo1 - cb; s1 = (s1 < m) ? s1 : m;
        int j = s0;
        for (; j + 16 <= s1; j += 16) {
            u32 v0 = sidx[wv][j];
            u32 v1 = sidx[wv][j + 1];
            u32 v2 = sidx[wv][j + 2];
            u32 v3 = sidx[wv][j + 3];
            u32 v4 = sidx[wv][j + 4];
            u32 v5 = sidx[wv][j + 5];
            u32 v6 = sidx[wv][j + 6];
            u32 v7 = sidx[wv][j + 7];
            u32 v8 = sidx[wv][j + 8];
            u32 v9 = sidx[wv][j + 9];
            u32 va = sidx[wv][j + 10];
            u32 vb = sidx[wv][j + 11];
            u32 vc = sidx[wv][j + 12];
            u32 vd = sidx[wv][j + 13];
            u32 ve = sidx[wv][j + 14];
            u32 vf = sidx[wv][j + 15];
            uint2 u0 = LD2(v0);
            uint2 u1 = LD2(v1);
            uint2 u2 = LD2(v2);
            uint2 u3 = LD2(v3);
            uint2 u4 = LD2(v4);
            uint2 u5 = LD2(v5);
            uint2 u6 = LD2(v6);
            uint2 u7 = LD2(v7);
            uint2 u8 = LD2(v8);
            uint2 u9 = LD2(v9);
            uint2 ua = LD2(va);
            uint2 ub = LD2(vb);
            uint2 uc = LD2(vc);
            uint2 ud = LD2(vd);
            uint2 ue = LD2(ve);
            uint2 uf = LD2(vf);
            ACC2(u0); ACC2(u1); ACC2(u2); ACC2(u3);
            ACC2(u4); ACC2(u5); ACC2(u6); ACC2(u7);
            ACC2(u8); ACC2(u9); ACC2(ua); ACC2(ub);
            ACC2(uc); ACC2(ud); ACC2(ue); ACC2(uf);
        }
        for (; j + 8 <= s1; j += 8) {
            u32 v0 = sidx[wv][j];
            u32 v1 = sidx[wv][j + 1];
            u32 v2 = sidx[wv][j + 2];
            u32 v3 = sidx[wv][j + 3];
            u32 v4 = sidx[wv][j + 4];
            u32 v5 = sidx[wv][j + 5];
            u32 v6 = sidx[wv][j + 6];
            u32 v7 = sidx[wv][j + 7];
            uint2 u0 = LD2(v0);
            uint2 u1 = LD2(v1);
            uint2 u2 = LD2(v2);
            uint2 u3 = LD2(v3);
            uint2 u4 = LD2(v4);
            uint2 u5 = LD2(v5);
            uint2 u6 = LD2(v6);
            uint2 u7 = LD2(v7);
            ACC2(u0); ACC2(u1); ACC2(u2); ACC2(u3);
            ACC2(u4); ACC2(u5); ACC2(u6); ACC2(u7);
        }
        for (; j + 4 <= s1; j += 4) {
            u32 v0 = sidx[wv][j];
            u32 v1 = sidx[wv][j + 1];
            u32 v2 = sidx[wv][j + 2];
            u32 v3 = sidx[wv][j + 3];
            uint2 u0 = LD2(v0);
            uint2 u1 = LD2(v1);
            uint2 u2 = LD2(v2);
            uint2 u3 = LD2(v3);
            ACC2(u0); ACC2(u1); ACC2(u2); ACC2(u3);
        }
        for (; j < s1; ++j) {
            u32 v0 = sidx[wv][j];
            uint2 u0 = LD2(v0);
            ACC2(u0);
        }
        __builtin_amdgcn_wave_barrier();  // reads done before next-chunk writes
    }
#undef LD2
#undef ACC2
    float inv = 1.0f / (float)(cnt > 0 ? cnt : 1);
    uint2 o;
    o.x = ((u32)f2bf(a1 * inv) << 16) | (u32)f2bf(a0 * inv);
    o.y = ((u32)f2bf(a3 * inv) << 16) | (u32)f2bf(a2 * inv);
    *(uint2*)(mg + (size_t)node * 8 + c * 2) = o;
}

// ---------------- MFMA GEMM: out = [self|mean](bf16) @ WT^T + b ----------------
// swapped-operand MFMA (D[ch][node]); WT staged once per block in swizzled
// LDS; 64 rows per wave. self/mean are group-major; A-fragment 16B chunks
// lie inside one group slice: gg = (ks&3)*2 + (quad>>1), col = (quad&1)*4.
template <int COUT, bool RELU, bool FINAL>
__global__ __launch_bounds__(256, 2) void sage_mfma(
    const u32* __restrict__ selfG, const u32* __restrict__ meanG,
    const u16* __restrict__ WT, const float* __restrict__ bias_f,
    void* __restrict__ out, const int* __restrict__ flags) {
    constexpr int CT = COUT / 16;            // 8 (L0/L1) or 4 (L2)
    __shared__ u16 wlds[256 * COUT];         // 64KB / 32KB, swizzled
    const int tid = threadIdx.x;
    const int wave = tid >> 6;
    const int lane = tid & 63;
    const int n16 = lane & 15;
    const int quad = lane >> 4;
    const int bfin = flags[1];

    // ---- stage WT into LDS, XOR-swizzled
    {
        const uint4* src = (const uint4*)WT;
        char* wb = (char*)wlds;
        constexpr int NITER = (COUT * 32) / 256;  // 16 or 8
#pragma unroll
        for (int i = 0; i < NITER; ++i) {
            int idx = i * 256 + tid;
            int c = idx >> 5;
            int off = (idx & 31) << 4;
            *(uint4*)(wb + c * 512 + (off ^ ((c & 7) << 4))) = src[idx];
        }
    }
    __syncthreads();

    // ---- per-lane A bases (4 M-tiles of 16 rows; n16 picks the row)
    const int rowb = blockIdx.x * 256 + wave * 64 + n16;
    const int gq = quad >> 1;
    const int wcol = (quad & 1) * 4;
    int rbase[4];
#pragma unroll
    for (int mt = 0; mt < 4; ++mt) {
        int r = rowb + mt * 16;
        r = (r < NN) ? r : (NN - 1);
        rbase[mt] = r * 8 + gq * SL + wcol;  // u32 index within (ks&3) pair
    }

    v4f acc[4][CT];
#pragma unroll
    for (int mt = 0; mt < 4; ++mt)
#pragma unroll
        for (int ct = 0; ct < CT; ++ct) acc[mt][ct] = (v4f)(0.f);

    const char* wb = (const char*)wlds;
    const int swz = (n16 & 7) << 4;
#pragma unroll
    for (int ks = 0; ks < 8; ++ks) {
        const u32* bp = (ks < 4) ? selfG : meanG;
        const int kof = (ks & 3) * 2 * SL;
        U4S8 nf[4];
#pragma unroll
        for (int mt = 0; mt < 4; ++mt)
            nf[mt].u = *(const uint4*)(bp + kof + rbase[mt]);
        U4S8 wf[CT];
#pragma unroll
        for (int ct = 0; ct < CT; ++ct) {
            int addr = (ct * 16 + n16) * 512 + ((ks * 64 + quad * 16) ^ swz);
            wf[ct].u = *(const uint4*)(wb + addr);
        }
#pragma unroll
        for (int mt = 0; mt < 4; ++mt)
#pragma unroll
            for (int ct = 0; ct < CT; ++ct)
                acc[mt][ct] = __builtin_amdgcn_mfma_f32_16x16x32_bf16(
                    wf[ct].s, nf[mt].s, acc[mt][ct], 0, 0, 0);
    }

    // ---- epilogue: lane holds node=rowb+mt*16, channels ct*16+quad*4+[0..3]
    float4 bv[CT];
#pragma unroll
    for (int ct = 0; ct < CT; ++ct)
        bv[ct] = *(const float4*)&bias_f[ct * 16 + quad * 4];

#pragma unroll
    for (int mt = 0; mt < 4; ++mt) {
        int row = rowb + mt * 16;
        if (row < NN) {
#pragma unroll
            for (int ct = 0; ct < CT; ++ct) {
                float v0 = acc[mt][ct][0] + bv[ct].x;
                float v1 = acc[mt][ct][1] + bv[ct].y;
                float v2 = acc[mt][ct][2] + bv[ct].z;
                float v3 = acc[mt][ct][3] + bv[ct].w;
                if (RELU) {
                    v0 = fmaxf(v0, 0.f);
                    v1 = fmaxf(v1, 0.f);
                    v2 = fmaxf(v2, 0.f);
                    v3 = fmaxf(v3, 0.f);
                }
                if (FINAL && !bfin) {
                    float4 o = {v0, v1, v2, v3};
                    *(float4*)((float*)out + (size_t)row * COUT + ct * 16 +
                               quad * 4) = o;
                } else {
                    uint2 o;
                    o.x = (u32)f2bf(v0) | ((u32)f2bf(v1) << 16);
                    o.y = (u32)f2bf(v2) | ((u32)f2bf(v3) << 16);
                    if (FINAL) {
                        // external bf16 output stays node-major
                        *(uint2*)((u16*)out + (size_t)row * COUT + ct * 16 +
                                  quad * 4) = o;
                    } else {
                        // group-major h write: group = ct, cols quad*2..+1
                        *(uint2*)((u32*)out + (size_t)ct * SL + (size_t)row * 8 +
                                  quad * 2) = o;
                    }
                }
            }
        }
    }
}

extern "C" void kernel_launch(void* const* d_in, const int* in_sizes, int n_in,
                              void* d_out, int out_size, void* d_ws,
                              size_t ws_size, hipStream_t stream) {
    const void* x = d_in[0];
    const void* ei = d_in[1];
    const void* Wl0 = d_in[2];
    const void* Wr0 = d_in[3];
    const void* b0 = d_in[4];
    const void* Wl1 = d_in[5];
    const void* Wr1 = d_in[6];
    const void* b1 = d_in[7];
    const void* Wl2 = d_in[8];
    const void* Wr2 = d_in[9];
    const void* b2 = d_in[10];

    char* ws = (char*)d_ws;
    size_t o = 0;
    auto alloc = [&](size_t bytes) {
        void* p = ws + o;
        o = (o + bytes + 511) & ~(size_t)511;
        return p;
    };
    int* flags = (int*)alloc(16);
    int* hist = (int*)alloc((size_t)NBUK * G * 4);
    int* bsums = (int*)alloc(256 * 4);
    int* off = (int*)alloc((NN + 1) * 4);
    int* ssrc = (int*)alloc((size_t)NE * 4);
    u32* ebuf = (u32*)alloc((size_t)NE * 4);             // packed src|dloc
    u32* xb = (u32*)alloc((size_t)(NN + 1) * 64 * 4);    // group-major + pad
    u32* meanB = (u32*)alloc((size_t)(NN + 1) * 64 * 4); // group-major + pad
    u32* h1 = (u32*)alloc((size_t)(NN + 1) * 64 * 4);
    u32* h2 = (u32*)alloc((size_t)(NN + 1) * 64 * 4);
    u16* WT0 = (u16*)alloc(256 * 128 * 2);
    u16* WT1 = (u16*)alloc(256 * 128 * 2);
    u16* WT2 = (u16*)alloc(256 * 64 * 2);
    float* bf0 = (float*)alloc(128 * 4);
    float* bf1 = (float*)alloc(128 * 4);
    float* bf2_ = (float*)alloc(64 * 4);

    constexpr int L = NBUK * G;              // 400384
    constexpr int NBLK = (L + 2047) / 2048;  // 196 (<= 256)
    constexpr int RB = (NN + 255) / 256;     // 391 (256 rows / block)
    constexpr int GB = 8 * ((NN + 63) / 64); // 12504 gather blocks

    detect_kernel<<<1, 256, 0, stream>>>((const u32*)ei, (const u32*)x, flags);
    conv_x<<<((NN + 1) * 64 + 255) / 256, 256, 0, stream>>>(x, flags, xb, h1,
                                                            h2);
    wt_prep_all<<<320, 256, 0, stream>>>(Wr0, Wl0, b0, Wr1, Wl1, b1, Wr2, Wl2,
                                         b2, flags, WT0, bf0, WT1, bf1, WT2,
                                         bf2_);

    // bucketed CSR build (packed u32 ebuf, 512 blocks for p1/p2)
    p1_hist<<<G, 256, 0, stream>>>(ei, flags, hist);
    scan_block_g<<<NBLK, 256, 0, stream>>>(hist, hist, bsums, L);
    scan_top_g<<<1, 256, 0, stream>>>(bsums, NBLK);
    scan_add_g<<<(L + 255) / 256, 256, 0, stream>>>(hist, bsums, L);
    p2_scatter<<<G, 256, 0, stream>>>(ei, flags, hist, ebuf);
    p3_build<<<NBUK, 256, 0, stream>>>(hist, ebuf, off, ssrc);

    // layer 0
    gather_mean_g<<<GB, 256, 0, stream>>>(xb, off, ssrc, meanB);
    sage_mfma<128, true, false><<<RB, 256, 0, stream>>>(xb, meanB, WT0, bf0,
                                                        h1, flags);
    // layer 1
    gather_mean_g<<<GB, 256, 0, stream>>>(h1, off, ssrc, meanB);
    sage_mfma<128, true, false><<<RB, 256, 0, stream>>>(h1, meanB, WT1, bf1,
                                                        h2, flags);
    // layer 2
    gather_mean_g<<<GB, 256, 0, stream>>>(h2, off, ssrc, meanB);
    sage_mfma<64, false, true><<<RB, 256, 0, stream>>>(h2, meanB, WT2, bf2_,
                                                       d_out, flags);
}